// Round 13
// baseline (606.681 us; speedup 1.0000x reference)
//
#include <hip/hip_runtime.h>
#include <math.h>

#define DIM 128
#define CAP 8192          // slots per bucket (mean fill 4096, sd ~64 -> never overflows)
#define BSHIFT 8          // 256 nodes per bucket
#define MAXNB 512         // max buckets supported (N <= 131072)

typedef __attribute__((ext_vector_type(8))) short bf16x8;
typedef __attribute__((ext_vector_type(8))) unsigned short us8;
typedef __attribute__((ext_vector_type(4))) float f32x4;

__device__ __forceinline__ unsigned short f2bf_rne(float f) {
    unsigned int u = __float_as_uint(f);
    unsigned int r = (u + 0x7FFFu + ((u >> 16) & 1u)) >> 16;
    return (unsigned short)r;
}
__device__ __forceinline__ float bf2f(unsigned short h) {
    return __uint_as_float(((unsigned int)h) << 16);
}

// ---------------------------------------------------------------- utilities
__global__ void k_zero_int(int* __restrict__ p, int n) {
    int i = blockIdx.x * blockDim.x + threadIdx.x;
    if (i < n) p[i] = 0;
}

// fp32 -> bf16 copy (for the aggregation gather operand), float4-vectorized
__global__ __launch_bounds__(256) void k_xcvt(const float* __restrict__ in,
                                              unsigned short* __restrict__ outb,
                                              int n4) {
    int i = blockIdx.x * 256 + threadIdx.x;
    int stride = gridDim.x * 256;
    for (; i < n4; i += stride) {
        float4 v = *(const float4*)(in + (size_t)i * 4);
        ushort4 o;
        o.x = f2bf_rne(v.x);
        o.y = f2bf_rne(v.y);
        o.z = f2bf_rne(v.z);
        o.w = f2bf_rne(v.w);
        *(ushort4*)(outb + (size_t)i * 4) = o;
    }
}

// one-time weight conversion: Wcat[layer][n][k] (k<128 self, k>=128 neigh)
// -> bf16 hi and lo planes, [2][128][256] each.
__global__ __launch_bounds__(256) void k_wcvt(const float* __restrict__ Ws1,
                                              const float* __restrict__ Wn1,
                                              const float* __restrict__ Ws2,
                                              const float* __restrict__ Wn2,
                                              unsigned short* __restrict__ Wh,
                                              unsigned short* __restrict__ Wl) {
    int i = blockIdx.x * 256 + threadIdx.x;   // 0 .. 65535
    int l = i >> 15;
    int rem = i & 32767;
    int n = rem >> 8;
    int k = rem & 255;
    const float* W = (k < 128) ? (l ? Ws2 : Ws1) : (l ? Wn2 : Wn1);
    float f = W[n * 128 + (k & 127)];
    unsigned short h = f2bf_rne(f);
    Wh[i] = h;
    Wl[i] = f2bf_rne(f - bf2f(h));
}

// Pass A (block-batched): LDS histogram over buckets, ONE global reservation
// atomic per (block,bucket), then LDS-cursor writes into reserved runs.
__global__ __launch_bounds__(256) void k_bucket(const int* __restrict__ src,
                                                const int* __restrict__ dst,
                                                int* __restrict__ bcur,
                                                unsigned int* __restrict__ tmpe,
                                                int E, int NB, int chunk) {
    __shared__ int hist[MAXNB];
    __shared__ int cur[MAXNB];
    int t = threadIdx.x;
    int begE = blockIdx.x * chunk;
    int endE = begE + chunk;
    if (endE > E) endE = E;

    hist[t] = 0;
    hist[t + 256] = 0;
    __syncthreads();

    for (int e = begE + t; e < endE; e += 256) {
        atomicAdd(&hist[dst[e] >> BSHIFT], 1);
    }
    __syncthreads();

    if (t < NB)  cur[t]  = atomicAdd(&bcur[t], hist[t]);
    int t2 = t + 256;
    if (t2 < NB) cur[t2] = atomicAdd(&bcur[t2], hist[t2]);
    __syncthreads();

    for (int e = begE + t; e < endE; e += 256) {
        int s = src[e];
        int d = dst[e];
        int b = d >> BSHIFT;
        int p = atomicAdd(&cur[b], 1);   // LDS atomic
        if (p < CAP) tmpe[(size_t)b * CAP + p] = (unsigned int)s | ((unsigned int)(d & 255) << 17);
    }
}

// Pass B: one workgroup per bucket; LDS stage + histogram + scan + regroup.
__global__ __launch_bounds__(256) void k_scatter(unsigned int* __restrict__ tmpe,
                                                 const int* __restrict__ bcur,
                                                 int* __restrict__ rs,
                                                 int* __restrict__ cnt,
                                                 int N) {
    __shared__ unsigned int se[CAP];   // 32 KB
    __shared__ int hist[256];
    __shared__ int sh[256];
    __shared__ int cur[256];
    int b = blockIdx.x;
    int t = threadIdx.x;
    size_t base = (size_t)b * CAP;
    int m = bcur[b];
    if (m > CAP) m = CAP;
    for (int i = t; i < m; i += 256) se[i] = tmpe[base + i];
    hist[t] = 0;
    __syncthreads();
    for (int i = t; i < m; i += 256) atomicAdd(&hist[se[i] >> 17], 1);
    __syncthreads();
    int v = hist[t];
    sh[t] = v;
    __syncthreads();
    int run = v;
    for (int off = 1; off < 256; off <<= 1) {
        int y = (t >= off) ? sh[t - off] : 0;
        __syncthreads();
        run += y;
        sh[t] = run;
        __syncthreads();
    }
    int excl = run - v;
    int node = (b << BSHIFT) + t;
    if (node < N) {
        rs[node] = (int)base + excl;
        cnt[node] = v;
    }
    cur[t] = excl;
    __syncthreads();
    for (int i = t; i < m; i += 256) {
        unsigned int pk = se[i];
        int d = pk >> 17;
        int p = atomicAdd(&cur[d], 1);
        tmpe[base + p] = pk & 0x1FFFFu;
    }
}

// fused aggregate + split-bf16 MFMA dual GEMM + (optional) L2-norm epilogue.
// Block = 64 dst nodes x 128 out cols, 4 waves (16 nodes each).
// Phase 1: gather bf16 rows, fp32 mean (bitwise-identical summation to the
//   old k_agg), convert mean->hi/lo bf16 in registers, write into swizzled
//   LDS planes Mh/Ml = the neighbor K-half (k=128..255) of the A operand.
// Phase 2: identical 4-chunk MFMA loop as the old k_gemm; chunks 0,1 stage
//   self rows (fp32->hi/lo) from global, chunks 2,3 read Mh/Ml directly.
// msg never touches global memory (saves 102 MB/layer + 2 dispatches).
template <bool FUSE_NORM>
__global__ __launch_bounds__(256) void k_fused(const float* __restrict__ Afp,
                                               const unsigned short* __restrict__ Ab,
                                               const int* __restrict__ rs,
                                               const int* __restrict__ cnt,
                                               const unsigned int* __restrict__ esrc,
                                               const unsigned short* __restrict__ Wh,
                                               const unsigned short* __restrict__ Wl,
                                               const float* __restrict__ bias,
                                               float* __restrict__ out,
                                               unsigned short* __restrict__ outb,
                                               int N, int layer) {
    __shared__ __align__(16) unsigned short Mh[2 * 64 * 64];   // 16 KB
    __shared__ __align__(16) unsigned short Ml[2 * 64 * 64];   // 16 KB
    __shared__ __align__(16) unsigned short Ah[64 * 64];       //  8 KB
    __shared__ __align__(16) unsigned short Al[64 * 64];       //  8 KB
    __shared__ __align__(16) unsigned short Bh[128 * 64];      // 16 KB
    __shared__ __align__(16) unsigned short Bl[128 * 64];      // 16 KB  => 80 KB, 2 blocks/CU
    int tid = threadIdx.x;
    int w = tid >> 6;
    int lane = tid & 63;
    int half = lane >> 5;
    int l32 = lane & 31;
    int l4 = lane & 15;
    int g = lane >> 4;
    int m0 = blockIdx.x * 64;
    const unsigned short* WhL = Wh + layer * 128 * 256;
    const unsigned short* WlL = Wl + layer * 128 * 256;

    // ---------------- phase 1: gather + mean -> Mh/Ml ----------------
    int c = l32 * 4;                     // 4 bf16 columns per lane
    for (int i = 0; i < 16; ++i) {
        int row = w * 16 + i;
        int node = m0 + row;
        int beg = 0, deg = 0;
        if (node < N) { beg = rs[node]; deg = cnt[node]; }
        int end = beg + deg;
        float ax = 0.f, ay = 0.f, az = 0.f, aw_ = 0.f;
        int e = beg + half;              // halves alternate edges (stride 2)
        for (; e + 6 < end; e += 8) {    // unroll 4
            int s0 = esrc[e];
            int s1 = esrc[e + 2];
            int s2 = esrc[e + 4];
            int s3 = esrc[e + 6];
            ushort4 u0 = *(const ushort4*)(Ab + (size_t)s0 * DIM + c);
            ushort4 u1 = *(const ushort4*)(Ab + (size_t)s1 * DIM + c);
            ushort4 u2 = *(const ushort4*)(Ab + (size_t)s2 * DIM + c);
            ushort4 u3 = *(const ushort4*)(Ab + (size_t)s3 * DIM + c);
            ax += (bf2f(u0.x) + bf2f(u1.x)) + (bf2f(u2.x) + bf2f(u3.x));
            ay += (bf2f(u0.y) + bf2f(u1.y)) + (bf2f(u2.y) + bf2f(u3.y));
            az += (bf2f(u0.z) + bf2f(u1.z)) + (bf2f(u2.z) + bf2f(u3.z));
            aw_ += (bf2f(u0.w) + bf2f(u1.w)) + (bf2f(u2.w) + bf2f(u3.w));
        }
        for (; e + 2 < end; e += 4) {    // tail unroll 2
            int s0 = esrc[e];
            int s1 = esrc[e + 2];
            ushort4 u0 = *(const ushort4*)(Ab + (size_t)s0 * DIM + c);
            ushort4 u1 = *(const ushort4*)(Ab + (size_t)s1 * DIM + c);
            ax += bf2f(u0.x) + bf2f(u1.x);
            ay += bf2f(u0.y) + bf2f(u1.y);
            az += bf2f(u0.z) + bf2f(u1.z);
            aw_ += bf2f(u0.w) + bf2f(u1.w);
        }
        if (e < end) {
            int s0 = esrc[e];
            ushort4 u0 = *(const ushort4*)(Ab + (size_t)s0 * DIM + c);
            ax += bf2f(u0.x);
            ay += bf2f(u0.y);
            az += bf2f(u0.z);
            aw_ += bf2f(u0.w);
        }
        ax += __shfl_xor(ax, 32);
        ay += __shfl_xor(ay, 32);
        az += __shfl_xor(az, 32);
        aw_ += __shfl_xor(aw_, 32);
        if (half == 0) {
            float invd = 1.0f / fmaxf((float)deg, 1.0f);
            float f0 = ax * invd, f1 = ay * invd, f2 = az * invd, f3 = aw_ * invd;
            ushort4 hv, lv;
            hv.x = f2bf_rne(f0); lv.x = f2bf_rne(f0 - bf2f(hv.x));
            hv.y = f2bf_rne(f1); lv.y = f2bf_rne(f1 - bf2f(hv.y));
            hv.z = f2bf_rne(f2); lv.z = f2bf_rne(f2 - bf2f(hv.z));
            hv.w = f2bf_rne(f3); lv.w = f2bf_rne(f3 - bf2f(hv.w));
            // c=4*l32 -> chunk_local=l32>>4, granule k8=(l32>>1)&7, elem 4*(l32&1)
            int ch = l32 >> 4;
            int k8 = (l32 >> 1) & 7;
            int us = ch * 4096 + row * 64 + ((k8 ^ (row & 7)) << 3) + ((l32 & 1) << 2);
            *(ushort4*)&Mh[us] = hv;
            *(ushort4*)&Ml[us] = lv;
        }
    }

    // ---------------- phase 2: MFMA over K=256 concat ----------------
    f32x4 acc[8];
#pragma unroll
    for (int ct = 0; ct < 8; ++ct) acc[ct] = (f32x4){0.f, 0.f, 0.f, 0.f};

    for (int chunk = 0; chunk < 4; ++chunk) {
        if (chunk < 2) {
            // stage self rows: 64 rows x 64 k, fp32 -> bf16 hi/lo, swizzled
#pragma unroll
            for (int i = 0; i < 2; ++i) {
                int seg = tid + i * 256;          // 512 segs of 8 k
                int row = seg >> 3, k8 = seg & 7;
                int m = m0 + row;
                float4 v0 = make_float4(0.f, 0.f, 0.f, 0.f);
                float4 v1 = make_float4(0.f, 0.f, 0.f, 0.f);
                if (m < N) {
                    const float* p = Afp + (size_t)m * DIM + chunk * 64 + k8 * 8;
                    v0 = *(const float4*)p;
                    v1 = *(const float4*)(p + 4);
                }
                float f[8] = {v0.x, v0.y, v0.z, v0.w, v1.x, v1.y, v1.z, v1.w};
                us8 hv, lv;
#pragma unroll
                for (int j = 0; j < 8; ++j) {
                    unsigned short h = f2bf_rne(f[j]);
                    hv[j] = h;
                    lv[j] = f2bf_rne(f[j] - bf2f(h));
                }
                int us = row * 64 + ((k8 ^ (row & 7)) << 3);
                *(us8*)&Ah[us] = hv;
                *(us8*)&Al[us] = lv;
            }
        }
        // stage B chunk: 128 n x 64 k from pre-converted planes, swizzled
#pragma unroll
        for (int i = 0; i < 4; ++i) {
            int seg = tid + i * 256;
            int n = seg >> 3, k8 = seg & 7;
            int gi = n * 256 + chunk * 64 + k8 * 8;
            us8 hv = *(const us8*)&WhL[gi];
            us8 lv = *(const us8*)&WlL[gi];
            int us = n * 64 + ((k8 ^ (n & 7)) << 3);
            *(us8*)&Bh[us] = hv;
            *(us8*)&Bl[us] = lv;
        }
        __syncthreads();
        int arow = w * 16 + l4;
#pragma unroll
        for (int ks = 0; ks < 2; ++ks) {
            int kidx = ks * 4 + g;
            bf16x8 ah, al;
            if (chunk < 2) {
                int us = arow * 64 + ((kidx ^ (arow & 7)) << 3);
                ah = *(const bf16x8*)&Ah[us];
                al = *(const bf16x8*)&Al[us];
            } else {
                int us = (chunk - 2) * 4096 + arow * 64 + ((kidx ^ (arow & 7)) << 3);
                ah = *(const bf16x8*)&Mh[us];
                al = *(const bf16x8*)&Ml[us];
            }
#pragma unroll
            for (int ct = 0; ct < 8; ++ct) {
                int n = ct * 16 + l4;
                int us = n * 64 + ((kidx ^ (n & 7)) << 3);
                bf16x8 bh = *(const bf16x8*)&Bh[us];
                bf16x8 bl = *(const bf16x8*)&Bl[us];
                acc[ct] = __builtin_amdgcn_mfma_f32_16x16x32_bf16(ah, bh, acc[ct], 0, 0, 0);
                acc[ct] = __builtin_amdgcn_mfma_f32_16x16x32_bf16(ah, bl, acc[ct], 0, 0, 0);
                acc[ct] = __builtin_amdgcn_mfma_f32_16x16x32_bf16(al, bh, acc[ct], 0, 0, 0);
            }
        }
        __syncthreads();
    }

    // ---------------- epilogue ----------------
    float bv[8];
#pragma unroll
    for (int ct = 0; ct < 8; ++ct) bv[ct] = bias[ct * 16 + l4];
    float vals[8][4];
#pragma unroll
    for (int ct = 0; ct < 8; ++ct)
#pragma unroll
        for (int r = 0; r < 4; ++r) vals[ct][r] = acc[ct][r] + bv[ct];
    if (FUSE_NORM) {
        float ss[4];
#pragma unroll
        for (int r = 0; r < 4; ++r) {
            float s = 0.f;
#pragma unroll
            for (int ct = 0; ct < 8; ++ct) s += vals[ct][r] * vals[ct][r];
            s += __shfl_xor(s, 1);
            s += __shfl_xor(s, 2);
            s += __shfl_xor(s, 4);
            s += __shfl_xor(s, 8);
            ss[r] = s;
        }
#pragma unroll
        for (int r = 0; r < 4; ++r) {
            float sc = 1.0f / fmaxf(sqrtf(ss[r]), 1e-12f);
#pragma unroll
            for (int ct = 0; ct < 8; ++ct) vals[ct][r] *= sc;
        }
    }
    int rbase = m0 + w * 16 + g * 4;
#pragma unroll
    for (int r = 0; r < 4; ++r) {
        int m = rbase + r;
        if (m < N) {
#pragma unroll
            for (int ct = 0; ct < 8; ++ct) {
                out[(size_t)m * DIM + ct * 16 + l4] = vals[ct][r];
                if (outb)
                    outb[(size_t)m * DIM + ct * 16 + l4] = f2bf_rne(vals[ct][r]);
            }
        }
    }
}

extern "C" void kernel_launch(void* const* d_in, const int* in_sizes, int n_in,
                              void* d_out, int out_size, void* d_ws, size_t ws_size,
                              hipStream_t stream) {
    const float* x   = (const float*)d_in[0];
    const int*   src = (const int*)d_in[1];
    const int*   dst = (const int*)d_in[2];
    const float* Ws1 = (const float*)d_in[3];
    const float* Wn1 = (const float*)d_in[4];
    const float* b1  = (const float*)d_in[5];
    const float* Ws2 = (const float*)d_in[6];
    const float* Wn2 = (const float*)d_in[7];
    const float* b2  = (const float*)d_in[8];
    float* out = (float*)d_out;

    int N = in_sizes[0] / DIM;
    int E = in_sizes[1];
    int NB = (N + (1 << BSHIFT) - 1) >> BSHIFT;

    // workspace carve-up (256B aligned)
    char* p = (char*)d_ws;
    size_t off = 0;
    auto carve = [&](size_t bytes) {
        void* r = p + off;
        off = (off + bytes + 255) & ~(size_t)255;
        return r;
    };
    unsigned int* tmpe = (unsigned int*)carve((size_t)NB * CAP * 4);
    int* bcur = (int*)carve((size_t)NB * 4);
    int* rs   = (int*)carve((size_t)N * 4);
    int* cnt  = (int*)carve((size_t)N * 4);
    float* h1  = (float*)carve((size_t)N * DIM * 4);
    unsigned short* xb  = (unsigned short*)carve((size_t)N * DIM * 2);
    unsigned short* h1b = (unsigned short*)carve((size_t)N * DIM * 2);
    unsigned short* Wh = (unsigned short*)carve((size_t)2 * 128 * 256 * 2);
    unsigned short* Wl = (unsigned short*)carve((size_t)2 * 128 * 256 * 2);

    // ---- one-time conversions ----
    k_wcvt<<<256, 256, 0, stream>>>(Ws1, Wn1, Ws2, Wn2, Wh, Wl);
    k_xcvt<<<2048, 256, 0, stream>>>(x, xb, N * DIM / 4);

    // ---- CSR build (bucketed two-pass, block-batched reservations) ----
    int grid_b = 256;
    int chunk = (E + grid_b - 1) / grid_b;
    k_zero_int<<<(NB + 255) / 256, 256, 0, stream>>>(bcur, NB);
    k_bucket<<<grid_b, 256, 0, stream>>>(src, dst, bcur, tmpe, E, NB, chunk);
    k_scatter<<<NB, 256, 0, stream>>>(tmpe, bcur, rs, cnt, N);

    // ---- layer 1 (fused agg+gemm; also emits bf16 h1 for layer-2 gather) ----
    int grid_f = (N + 63) / 64;
    k_fused<false><<<grid_f, 256, 0, stream>>>(x, xb, rs, cnt, tmpe, Wh, Wl, b1, h1, h1b, N, 0);

    // ---- layer 2 (fused agg+gemm+norm) ----
    k_fused<true><<<grid_f, 256, 0, stream>>>(h1, h1b, rs, cnt, tmpe, Wh, Wl, b2, out, nullptr, N, 1);
}

// Round 14
// 378.449 us; speedup vs baseline: 1.6031x; 1.6031x over previous
//
#include <hip/hip_runtime.h>
#include <math.h>

#define DIM 128
#define CAP 8192          // slots per bucket (mean fill 4096, sd ~64 -> never overflows)
#define BSHIFT 8          // 256 nodes per bucket
#define MAXNB 512         // max buckets supported (N <= 131072)

typedef __attribute__((ext_vector_type(8))) short bf16x8;
typedef __attribute__((ext_vector_type(8))) unsigned short us8;
typedef __attribute__((ext_vector_type(4))) float f32x4;

__device__ __forceinline__ unsigned short f2bf_rne(float f) {
    unsigned int u = __float_as_uint(f);
    unsigned int r = (u + 0x7FFFu + ((u >> 16) & 1u)) >> 16;
    return (unsigned short)r;
}
__device__ __forceinline__ float bf2f(unsigned short h) {
    return __uint_as_float(((unsigned int)h) << 16);
}

// ---------------------------------------------------------------- utilities
// fp32 -> bf16 hi/lo plane split (for gather + GEMM self operand)
__global__ __launch_bounds__(256) void k_xcvt(const float* __restrict__ in,
                                              unsigned short* __restrict__ outh,
                                              unsigned short* __restrict__ outl,
                                              int n4) {
    int i = blockIdx.x * 256 + threadIdx.x;
    int stride = gridDim.x * 256;
    for (; i < n4; i += stride) {
        float4 v = *(const float4*)(in + (size_t)i * 4);
        ushort4 h, l;
        h.x = f2bf_rne(v.x); l.x = f2bf_rne(v.x - bf2f(h.x));
        h.y = f2bf_rne(v.y); l.y = f2bf_rne(v.y - bf2f(h.y));
        h.z = f2bf_rne(v.z); l.z = f2bf_rne(v.z - bf2f(h.z));
        h.w = f2bf_rne(v.w); l.w = f2bf_rne(v.w - bf2f(h.w));
        *(ushort4*)(outh + (size_t)i * 4) = h;
        *(ushort4*)(outl + (size_t)i * 4) = l;
    }
}

// one-time weight conversion (also zeroes bcur): Wcat[layer][n][k]
// (k<128 self, k>=128 neigh) -> bf16 hi and lo planes, [2][128][256] each.
__global__ __launch_bounds__(256) void k_wcvt(const float* __restrict__ Ws1,
                                              const float* __restrict__ Wn1,
                                              const float* __restrict__ Ws2,
                                              const float* __restrict__ Wn2,
                                              unsigned short* __restrict__ Wh,
                                              unsigned short* __restrict__ Wl,
                                              int* __restrict__ bcur, int NB) {
    int i = blockIdx.x * 256 + threadIdx.x;   // 0 .. 65535
    if (i < NB) bcur[i] = 0;
    int l = i >> 15;
    int rem = i & 32767;
    int n = rem >> 8;
    int k = rem & 255;
    const float* W = (k < 128) ? (l ? Ws2 : Ws1) : (l ? Wn2 : Wn1);
    float f = W[n * 128 + (k & 127)];
    unsigned short h = f2bf_rne(f);
    Wh[i] = h;
    Wl[i] = f2bf_rne(f - bf2f(h));
}

// Pass A (block-batched): LDS histogram over buckets, ONE global reservation
// atomic per (block,bucket), then LDS-cursor writes into reserved runs.
__global__ __launch_bounds__(256) void k_bucket(const int* __restrict__ src,
                                                const int* __restrict__ dst,
                                                int* __restrict__ bcur,
                                                unsigned int* __restrict__ tmpe,
                                                int E, int NB, int chunk) {
    __shared__ int hist[MAXNB];
    __shared__ int cur[MAXNB];
    int t = threadIdx.x;
    int begE = blockIdx.x * chunk;
    int endE = begE + chunk;
    if (endE > E) endE = E;

    hist[t] = 0;
    hist[t + 256] = 0;
    __syncthreads();

    for (int e = begE + t; e < endE; e += 256) {
        atomicAdd(&hist[dst[e] >> BSHIFT], 1);
    }
    __syncthreads();

    if (t < NB)  cur[t]  = atomicAdd(&bcur[t], hist[t]);
    int t2 = t + 256;
    if (t2 < NB) cur[t2] = atomicAdd(&bcur[t2], hist[t2]);
    __syncthreads();

    for (int e = begE + t; e < endE; e += 256) {
        int s = src[e];
        int d = dst[e];
        int b = d >> BSHIFT;
        int p = atomicAdd(&cur[b], 1);   // LDS atomic
        if (p < CAP) tmpe[(size_t)b * CAP + p] = (unsigned int)s | ((unsigned int)(d & 255) << 17);
    }
}

// Pass B: one workgroup per bucket; LDS stage + histogram + scan + regroup.
__global__ __launch_bounds__(256) void k_scatter(unsigned int* __restrict__ tmpe,
                                                 const int* __restrict__ bcur,
                                                 int* __restrict__ rs,
                                                 int* __restrict__ cnt,
                                                 int N) {
    __shared__ unsigned int se[CAP];   // 32 KB
    __shared__ int hist[256];
    __shared__ int sh[256];
    __shared__ int cur[256];
    int b = blockIdx.x;
    int t = threadIdx.x;
    size_t base = (size_t)b * CAP;
    int m = bcur[b];
    if (m > CAP) m = CAP;
    for (int i = t; i < m; i += 256) se[i] = tmpe[base + i];
    hist[t] = 0;
    __syncthreads();
    for (int i = t; i < m; i += 256) atomicAdd(&hist[se[i] >> 17], 1);
    __syncthreads();
    int v = hist[t];
    sh[t] = v;
    __syncthreads();
    int run = v;
    for (int off = 1; off < 256; off <<= 1) {
        int y = (t >= off) ? sh[t - off] : 0;
        __syncthreads();
        run += y;
        sh[t] = run;
        __syncthreads();
    }
    int excl = run - v;
    int node = (b << BSHIFT) + t;
    if (node < N) {
        rs[node] = (int)base + excl;
        cnt[node] = v;
    }
    cur[t] = excl;
    __syncthreads();
    for (int i = t; i < m; i += 256) {
        unsigned int pk = se[i];
        int d = pk >> 17;
        int p = atomicAdd(&cur[d], 1);
        tmpe[base + p] = pk & 0x1FFFFu;
    }
}

// mean-aggregate from BF16 rows: one wave per dst node; half-wave (32 lanes
// x ushort4 = 256B) covers a full row; halves alternate edges; unroll-4 per
// half => 8 independent 256B row-gathers in flight. fp32 accumulate; output
// written directly as hi/lo bf16 planes (register split, value-identical to
// splitting fp32 msg later).
__global__ __launch_bounds__(256) void k_agg(const unsigned short* __restrict__ in,
                                             const int* __restrict__ rs,
                                             const int* __restrict__ cnt,
                                             const unsigned int* __restrict__ esrc,
                                             unsigned short* __restrict__ mh,
                                             unsigned short* __restrict__ ml,
                                             int N) {
    int w = threadIdx.x >> 6;            // wave within block
    int half = (threadIdx.x >> 5) & 1;   // half-wave id
    int l32 = threadIdx.x & 31;          // lane within half
    int node = blockIdx.x * 4 + w;
    if (node >= N) return;
    int beg = rs[node];
    int deg = cnt[node];
    int end = beg + deg;
    int c = l32 * 4;                     // 4 bf16 columns per lane
    float ax = 0.f, ay = 0.f, az = 0.f, aw = 0.f;
    int e = beg + half;                  // this half's edges: stride 2
    for (; e + 6 < end; e += 8) {        // unroll 4
        int s0 = esrc[e];
        int s1 = esrc[e + 2];
        int s2 = esrc[e + 4];
        int s3 = esrc[e + 6];
        ushort4 u0 = *(const ushort4*)(in + (size_t)s0 * DIM + c);
        ushort4 u1 = *(const ushort4*)(in + (size_t)s1 * DIM + c);
        ushort4 u2 = *(const ushort4*)(in + (size_t)s2 * DIM + c);
        ushort4 u3 = *(const ushort4*)(in + (size_t)s3 * DIM + c);
        ax += (bf2f(u0.x) + bf2f(u1.x)) + (bf2f(u2.x) + bf2f(u3.x));
        ay += (bf2f(u0.y) + bf2f(u1.y)) + (bf2f(u2.y) + bf2f(u3.y));
        az += (bf2f(u0.z) + bf2f(u1.z)) + (bf2f(u2.z) + bf2f(u3.z));
        aw += (bf2f(u0.w) + bf2f(u1.w)) + (bf2f(u2.w) + bf2f(u3.w));
    }
    for (; e + 2 < end; e += 4) {        // tail unroll 2
        int s0 = esrc[e];
        int s1 = esrc[e + 2];
        ushort4 u0 = *(const ushort4*)(in + (size_t)s0 * DIM + c);
        ushort4 u1 = *(const ushort4*)(in + (size_t)s1 * DIM + c);
        ax += bf2f(u0.x) + bf2f(u1.x);
        ay += bf2f(u0.y) + bf2f(u1.y);
        az += bf2f(u0.z) + bf2f(u1.z);
        aw += bf2f(u0.w) + bf2f(u1.w);
    }
    if (e < end) {
        int s0 = esrc[e];
        ushort4 u0 = *(const ushort4*)(in + (size_t)s0 * DIM + c);
        ax += bf2f(u0.x);
        ay += bf2f(u0.y);
        az += bf2f(u0.z);
        aw += bf2f(u0.w);
    }
    ax += __shfl_xor(ax, 32);
    ay += __shfl_xor(ay, 32);
    az += __shfl_xor(az, 32);
    aw += __shfl_xor(aw, 32);
    if (half == 0) {
        float invd = 1.0f / fmaxf((float)deg, 1.0f);
        float f0 = ax * invd, f1 = ay * invd, f2 = az * invd, f3 = aw * invd;
        ushort4 hv, lv;
        hv.x = f2bf_rne(f0); lv.x = f2bf_rne(f0 - bf2f(hv.x));
        hv.y = f2bf_rne(f1); lv.y = f2bf_rne(f1 - bf2f(hv.y));
        hv.z = f2bf_rne(f2); lv.z = f2bf_rne(f2 - bf2f(hv.z));
        hv.w = f2bf_rne(f3); lv.w = f2bf_rne(f3 - bf2f(hv.w));
        *(ushort4*)(mh + (size_t)node * DIM + c) = hv;
        *(ushort4*)(ml + (size_t)node * DIM + c) = lv;
    }
}

// split-bf16 MFMA dual GEMM over pre-split hi/lo planes.
// Block = 64 rows x 128 cols, 4 waves (16 rows each) — geometry validated in
// the R13 fused run. K concat=256, chunks of 64: chunks 0,1 from self planes
// (Sh/Sl), chunks 2,3 from neighbor-mean planes (Mh/Ml). Staging is pure us8
// plane copies (no conversion VALU). 3-term hi/lo MFMA. LDS 48 KB -> 3 blk/CU.
// FUSE_NORM: L2-normalize + write fp32 out. Else: write hi/lo planes only.
template <bool FUSE_NORM>
__global__ __launch_bounds__(256) void k_gemm(const unsigned short* __restrict__ Sh,
                                              const unsigned short* __restrict__ Sl,
                                              const unsigned short* __restrict__ Mhp,
                                              const unsigned short* __restrict__ Mlp,
                                              const unsigned short* __restrict__ Wh,
                                              const unsigned short* __restrict__ Wl,
                                              const float* __restrict__ bias,
                                              float* __restrict__ out,
                                              unsigned short* __restrict__ outh,
                                              unsigned short* __restrict__ outl,
                                              int N, int layer) {
    __shared__ __align__(16) unsigned short Ah[64 * 64];       //  8 KB
    __shared__ __align__(16) unsigned short Al[64 * 64];       //  8 KB
    __shared__ __align__(16) unsigned short Bh[128 * 64];      // 16 KB
    __shared__ __align__(16) unsigned short Bl[128 * 64];      // 16 KB => 48 KB
    int tid = threadIdx.x;
    int w = tid >> 6;
    int lane = tid & 63;
    int l4 = lane & 15;
    int g = lane >> 4;
    int m0 = blockIdx.x * 64;
    const unsigned short* WhL = Wh + layer * 128 * 256;
    const unsigned short* WlL = Wl + layer * 128 * 256;

    f32x4 acc[8];
#pragma unroll
    for (int ct = 0; ct < 8; ++ct) acc[ct] = (f32x4){0.f, 0.f, 0.f, 0.f};

    for (int chunk = 0; chunk < 4; ++chunk) {
        const unsigned short* srcH = (chunk < 2) ? Sh : Mhp;
        const unsigned short* srcL = (chunk < 2) ? Sl : Mlp;
        int kc = (chunk & 1) * 64;
        // stage A: 64 rows x 64 k = 512 us8 segs, 2 per thread
#pragma unroll
        for (int i = 0; i < 2; ++i) {
            int seg = tid + i * 256;
            int row = seg >> 3, k8 = seg & 7;
            int m = m0 + row;
            us8 hv = {0, 0, 0, 0, 0, 0, 0, 0};
            us8 lv = {0, 0, 0, 0, 0, 0, 0, 0};
            if (m < N) {
                size_t gi = (size_t)m * DIM + kc + k8 * 8;
                hv = *(const us8*)&srcH[gi];
                lv = *(const us8*)&srcL[gi];
            }
            int us = row * 64 + ((k8 ^ (row & 7)) << 3);
            *(us8*)&Ah[us] = hv;
            *(us8*)&Al[us] = lv;
        }
        // stage B: 128 n x 64 k = 1024 us8 segs, 4 per thread
#pragma unroll
        for (int i = 0; i < 4; ++i) {
            int seg = tid + i * 256;
            int n = seg >> 3, k8 = seg & 7;
            int gi = n * 256 + chunk * 64 + k8 * 8;
            us8 hv = *(const us8*)&WhL[gi];
            us8 lv = *(const us8*)&WlL[gi];
            int us = n * 64 + ((k8 ^ (n & 7)) << 3);
            *(us8*)&Bh[us] = hv;
            *(us8*)&Bl[us] = lv;
        }
        __syncthreads();
        int arow = w * 16 + l4;
#pragma unroll
        for (int ks = 0; ks < 2; ++ks) {
            int kidx = ks * 4 + g;
            int usa = arow * 64 + ((kidx ^ (arow & 7)) << 3);
            bf16x8 ah = *(const bf16x8*)&Ah[usa];
            bf16x8 al = *(const bf16x8*)&Al[usa];
#pragma unroll
            for (int ct = 0; ct < 8; ++ct) {
                int n = ct * 16 + l4;
                int usb = n * 64 + ((kidx ^ (n & 7)) << 3);
                bf16x8 bh = *(const bf16x8*)&Bh[usb];
                bf16x8 bl = *(const bf16x8*)&Bl[usb];
                acc[ct] = __builtin_amdgcn_mfma_f32_16x16x32_bf16(ah, bh, acc[ct], 0, 0, 0);
                acc[ct] = __builtin_amdgcn_mfma_f32_16x16x32_bf16(ah, bl, acc[ct], 0, 0, 0);
                acc[ct] = __builtin_amdgcn_mfma_f32_16x16x32_bf16(al, bh, acc[ct], 0, 0, 0);
            }
        }
        __syncthreads();
    }

    // ---------------- epilogue ----------------
    float bv[8];
#pragma unroll
    for (int ct = 0; ct < 8; ++ct) bv[ct] = bias[ct * 16 + l4];
    float vals[8][4];
#pragma unroll
    for (int ct = 0; ct < 8; ++ct)
#pragma unroll
        for (int r = 0; r < 4; ++r) vals[ct][r] = acc[ct][r] + bv[ct];
    if (FUSE_NORM) {
        float ss[4];
#pragma unroll
        for (int r = 0; r < 4; ++r) {
            float s = 0.f;
#pragma unroll
            for (int ct = 0; ct < 8; ++ct) s += vals[ct][r] * vals[ct][r];
            s += __shfl_xor(s, 1);
            s += __shfl_xor(s, 2);
            s += __shfl_xor(s, 4);
            s += __shfl_xor(s, 8);
            ss[r] = s;
        }
#pragma unroll
        for (int r = 0; r < 4; ++r) {
            float sc = 1.0f / fmaxf(sqrtf(ss[r]), 1e-12f);
#pragma unroll
            for (int ct = 0; ct < 8; ++ct) vals[ct][r] *= sc;
        }
    }
    int rbase = m0 + w * 16 + g * 4;
#pragma unroll
    for (int r = 0; r < 4; ++r) {
        int m = rbase + r;
        if (m < N) {
#pragma unroll
            for (int ct = 0; ct < 8; ++ct) {
                if (FUSE_NORM) {
                    out[(size_t)m * DIM + ct * 16 + l4] = vals[ct][r];
                } else {
                    unsigned short h = f2bf_rne(vals[ct][r]);
                    outh[(size_t)m * DIM + ct * 16 + l4] = h;
                    outl[(size_t)m * DIM + ct * 16 + l4] = f2bf_rne(vals[ct][r] - bf2f(h));
                }
            }
        }
    }
}

extern "C" void kernel_launch(void* const* d_in, const int* in_sizes, int n_in,
                              void* d_out, int out_size, void* d_ws, size_t ws_size,
                              hipStream_t stream) {
    const float* x   = (const float*)d_in[0];
    const int*   src = (const int*)d_in[1];
    const int*   dst = (const int*)d_in[2];
    const float* Ws1 = (const float*)d_in[3];
    const float* Wn1 = (const float*)d_in[4];
    const float* b1  = (const float*)d_in[5];
    const float* Ws2 = (const float*)d_in[6];
    const float* Wn2 = (const float*)d_in[7];
    const float* b2  = (const float*)d_in[8];
    float* out = (float*)d_out;

    int N = in_sizes[0] / DIM;
    int E = in_sizes[1];
    int NB = (N + (1 << BSHIFT) - 1) >> BSHIFT;

    // workspace carve-up (256B aligned)
    char* p = (char*)d_ws;
    size_t off = 0;
    auto carve = [&](size_t bytes) {
        void* r = p + off;
        off = (off + bytes + 255) & ~(size_t)255;
        return r;
    };
    unsigned int* tmpe = (unsigned int*)carve((size_t)NB * CAP * 4);
    int* bcur = (int*)carve((size_t)NB * 4);
    int* rs   = (int*)carve((size_t)N * 4);
    int* cnt  = (int*)carve((size_t)N * 4);
    unsigned short* xh  = (unsigned short*)carve((size_t)N * DIM * 2);
    unsigned short* xl  = (unsigned short*)carve((size_t)N * DIM * 2);
    unsigned short* h1h = (unsigned short*)carve((size_t)N * DIM * 2);
    unsigned short* h1l = (unsigned short*)carve((size_t)N * DIM * 2);
    unsigned short* mh  = (unsigned short*)carve((size_t)N * DIM * 2);
    unsigned short* ml  = (unsigned short*)carve((size_t)N * DIM * 2);
    unsigned short* Wh = (unsigned short*)carve((size_t)2 * 128 * 256 * 2);
    unsigned short* Wl = (unsigned short*)carve((size_t)2 * 128 * 256 * 2);

    // ---- one-time conversions (k_wcvt also zeroes bcur) ----
    k_wcvt<<<256, 256, 0, stream>>>(Ws1, Wn1, Ws2, Wn2, Wh, Wl, bcur, NB);
    k_xcvt<<<2048, 256, 0, stream>>>(x, xh, xl, N * DIM / 4);

    // ---- CSR build (bucketed two-pass, block-batched reservations) ----
    int grid_b = 256;
    int chunk = (E + grid_b - 1) / grid_b;
    k_bucket<<<grid_b, 256, 0, stream>>>(src, dst, bcur, tmpe, E, NB, chunk);
    k_scatter<<<NB, 256, 0, stream>>>(tmpe, bcur, rs, cnt, N);

    // ---- layer 1 ----
    k_agg<<<(N + 3) / 4, 256, 0, stream>>>(xh, rs, cnt, tmpe, mh, ml, N);
    k_gemm<false><<<(N + 63) / 64, 256, 0, stream>>>(xh, xl, mh, ml, Wh, Wl, b1,
                                                     nullptr, h1h, h1l, N, 0);

    // ---- layer 2 (norm fused into epilogue) ----
    k_agg<<<(N + 3) / 4, 256, 0, stream>>>(h1h, rs, cnt, tmpe, mh, ml, N);
    k_gemm<true><<<(N + 63) / 64, 256, 0, stream>>>(h1h, h1l, mh, ml, Wh, Wl, b2,
                                                    out, nullptr, nullptr, N, 1);
}